// Round 9
// baseline (2687.010 us; speedup 1.0000x reference)
//
#include <hip/hip_runtime.h>
#include <hip/hip_bf16.h>

#define T_STEPS 32
#define BATCH 256
#define EDIM 512
#define HDIM 512
#define G4 2048       // 4*H
#define VOCAB 3000
#define VPAD 3072

typedef short bf16x8 __attribute__((ext_vector_type(8)));
typedef float f32x4 __attribute__((ext_vector_type(4)));

__device__ __forceinline__ unsigned short f2b(float f){
  union { float f; unsigned int u; } x; x.f = f;
  unsigned int u = x.u;
  unsigned int r = (u + 0x7fffu + ((u >> 16) & 1u)) >> 16;
  return (unsigned short)r;
}
__device__ __forceinline__ float b2f(unsigned short h){
  union { unsigned int u; float f; } x; x.u = ((unsigned int)h) << 16;
  return x.f;
}
__device__ __forceinline__ float sigm(float x){ return 1.0f / (1.0f + expf(-x)); }

__device__ __forceinline__ void gload_lds16(const unsigned short* g, unsigned short* l){
  __builtin_amdgcn_global_load_lds(
      (const __attribute__((address_space(1))) unsigned int*)g,
      (__attribute__((address_space(3))) unsigned int*)l, 16, 0, 0);
}

// ---------------- small prep kernels ----------------

__global__ void k_cvt_w(const float* __restrict__ wih, const float* __restrict__ whh,
                        unsigned short* __restrict__ o_ih, unsigned short* __restrict__ o_hh){
  int i = blockIdx.x * blockDim.x + threadIdx.x;   // over 2 * G4*512
  int n1 = G4 * EDIM;
  if (i < n1) o_ih[i] = f2b(wih[i]);
  else { int j = i - n1; if (j < G4 * HDIM) o_hh[j] = f2b(whh[j]); }
}

__global__ void k_cvt_wout(const float* __restrict__ in, unsigned short* __restrict__ out){
  int i = blockIdx.x * blockDim.x + threadIdx.x; // over VPAD*1024
  if (i >= VPAD * 1024) return;
  int r = i >> 10, c = i & 1023;
  float v = (r < VOCAB) ? in[r * 1024 + c] : 0.0f;
  out[i] = f2b(v);
}

__global__ void k_build_xs(const float* __restrict__ img, const float* __restrict__ txt,
                           const float* __restrict__ emb, const int* __restrict__ ans,
                           unsigned short* __restrict__ xs){
  int i = blockIdx.x * blockDim.x + threadIdx.x; // over T*B*E
  if (i >= T_STEPS * BATCH * EDIM) return;
  int e = i & (EDIM - 1);
  int r = i >> 9;              // t*B + b
  int t = r >> 8, b = r & 255;
  float v;
  if (t == 0) v = (e < 256) ? img[b * 256 + e] : txt[b * 256 + (e - 256)];
  else { int tok = ans[b * T_STEPS + (t - 1)]; v = emb[(size_t)tok * EDIM + e]; }
  xs[i] = f2b(v);
}

// batch_sizes, packed row offsets, total rows, dest->src row map
__global__ void k_lens(const int* __restrict__ lengths, int* __restrict__ bs,
                       int* __restrict__ roff, int* __restrict__ meta,
                       int* __restrict__ rmap){
  __shared__ int s[T_STEPS];
  __shared__ int sroff[T_STEPS + 1];
  int t = threadIdx.x; // 64 threads
  if (t < T_STEPS){
    int c = 0;
    for (int i = 0; i < BATCH; i++) c += (lengths[i] > t) ? 1 : 0;
    s[t] = c; bs[t] = c;
  }
  __syncthreads();
  if (t == 0){
    int acc = 0;
    for (int u = 0; u < T_STEPS; u++){ sroff[u] = acc; roff[u] = acc; acc += s[u]; }
    sroff[T_STEPS] = acc;
    meta[0] = acc;
  }
  __syncthreads();
  int ntot = sroff[T_STEPS];
  for (int r = t; r < T_STEPS * BATCH; r += 64){
    int tt = r >> 8, b = r & 255;
    if (b < s[tt]) rmap[sroff[tt] + b] = r;
  }
  for (int r = ntot + t; r < T_STEPS * BATCH; r += 64) rmap[r] = -1;
}

// ---------------- staged 128x128 GEMM core, BK=64, XOR-swizzled LDS (round-7) ----------------
template<int K>
__device__ __forceinline__ void gemm_tile(const unsigned short* __restrict__ A,
                                          const unsigned short* __restrict__ B,
                                          int row0, int col0,
                                          unsigned short* As, unsigned short* Bs,
                                          f32x4 acc[4][4]){
  const int tid = threadIdx.x, w = tid >> 6, l = tid & 63;
  const int la = l & 15, lkq = l >> 4;
  const int sr = l >> 3;            // row within 8-row staging group
  const int ss = (l & 7) ^ sr;      // pre-swizzled source slot
  const int wr = (w >> 1) * 64, wc = (w & 1) * 64;
  const unsigned short* gA = A + (size_t)(row0 + w * 32 + sr) * K + ss * 8;
  const unsigned short* gB = B + (size_t)(col0 + w * 32 + sr) * K + ss * 8;
  unsigned short* lA = As + (w * 32) * 64;
  unsigned short* lB = Bs + (w * 32) * 64;
  for (int k0 = 0; k0 < K; k0 += 64){
#pragma unroll
    for (int i = 0; i < 4; i++){
      gload_lds16(gA + (size_t)i * 8 * K + k0, lA + i * 8 * 64);
      gload_lds16(gB + (size_t)i * 8 * K + k0, lB + i * 8 * 64);
    }
    __syncthreads();
#pragma unroll
    for (int kk = 0; kk < 2; kk++){
      bf16x8 a[4], b[4];
#pragma unroll
      for (int i = 0; i < 4; i++){
        int r = wr + i * 16 + la;
        a[i] = *(const bf16x8*)(As + r * 64 + (((kk * 4 + lkq) ^ (r & 7)) << 3));
      }
#pragma unroll
      for (int i = 0; i < 4; i++){
        int r = wc + i * 16 + la;
        b[i] = *(const bf16x8*)(Bs + r * 64 + (((kk * 4 + lkq) ^ (r & 7)) << 3));
      }
#pragma unroll
      for (int mi = 0; mi < 4; mi++)
#pragma unroll
        for (int ni = 0; ni < 4; ni++)
          acc[mi][ni] = __builtin_amdgcn_mfma_f32_16x16x32_bf16(a[mi], b[ni], acc[mi][ni], 0, 0, 0);
    }
    __syncthreads();
  }
}

// ---------------- GEMM 1: XW = xs @ W_ih^T + b_ih + b_hh (bf16 out) ----------------
__global__ __launch_bounds__(256) void k_gemm_xw(const unsigned short* __restrict__ A,
                                                 const unsigned short* __restrict__ W,
                                                 const float* __restrict__ bih,
                                                 const float* __restrict__ bhh,
                                                 unsigned short* __restrict__ C){
  __shared__ unsigned short As[128 * 64], Bs[128 * 64];
  int row0 = blockIdx.x * 128, col0 = blockIdx.y * 128;
  f32x4 acc[4][4] = {};
  gemm_tile<EDIM>(A, W, row0, col0, As, Bs, acc);
  int tid = threadIdx.x, w = tid >> 6, l = tid & 63;
  int la = l & 15, r4 = (l >> 4) * 4;
  int wr = (w >> 1) * 64, wc = (w & 1) * 64;
#pragma unroll
  for (int ni = 0; ni < 4; ni++){
    int col = col0 + wc + ni * 16 + la;
    float bias = bih[col] + bhh[col];
#pragma unroll
    for (int mi = 0; mi < 4; mi++)
#pragma unroll
      for (int j = 0; j < 4; j++){
        int row = row0 + wr + mi * 16 + r4 + j;
        C[(size_t)row * G4 + col] = f2b(acc[mi][ni][j] + bias);
      }
  }
}

// ---------------- single-launch LSTM chain: 16 blocks x 512 thr, row-local ----------------
// Block owns 16 batch rows for ALL steps; h lives in LDS (swizzled) across steps.
// Wave w owns h-cols [64w,64w+64) for all 4 gates -> cell update lane-local.
// c + skip history in registers; Whh streamed from (XCD-resident) L2 each step.
__global__ __launch_bounds__(512, 1) void k_lstm_chain(
    const unsigned short* __restrict__ XW,   // [T][B][2048] bf16
    const unsigned short* __restrict__ Whh,  // [2048][512] bf16
    const float* __restrict__ h0,
    const float* __restrict__ c0,
    unsigned short* __restrict__ hs,
    unsigned short* __restrict__ cs){
  __shared__ unsigned short hL[16 * 512];    // row r: 64 16B slots, slot ^= (r&7)
  const int tid = threadIdx.x;
  const int w = tid >> 6, l = tid & 63;
  const int la = l & 15, lkq = l >> 4;
  const int r0 = blockIdx.x * 16;
  // ---- init hL from h0 (f32 -> bf16, swizzled) ----
  for (int idx = tid; idx < 16 * 64; idx += 512){
    int r = idx >> 6, s = idx & 63;
    const float* hp = h0 + (size_t)(r0 + r) * HDIM + s * 8;
    bf16x8 hv;
#pragma unroll
    for (int j = 0; j < 8; j++) hv[j] = (short)f2b(hp[j]);
    *(bf16x8*)(hL + r * 512 + ((s ^ (r & 7)) << 3)) = hv;
  }
  // ---- per-lane cell state: rows lkq*4+j, cols w*64 + nt*16 + la (nt=0..3) ----
  float cx[4][4];                       // [nt][j], fp32
  unsigned hm1h[4][2], hm1c[4][2], hm2h[4][2], hm2c[4][2];  // bf16-packed history
#pragma unroll
  for (int nt = 0; nt < 4; nt++){
#pragma unroll
    for (int j = 0; j < 4; j++)
      cx[nt][j] = c0[(size_t)(r0 + lkq * 4 + j) * HDIM + w * 64 + nt * 16 + la];
    hm1h[nt][0] = hm1h[nt][1] = hm1c[nt][0] = hm1c[nt][1] = 0u;
    hm2h[nt][0] = hm2h[nt][1] = hm2c[nt][0] = hm2c[nt][1] = 0u;
  }
  __syncthreads();
  // Whh fragment base: lane la covers gate-col (g*512 + w*64 + nt*16 + la)
  const unsigned short* Bbase = Whh + (size_t)(w * 64 + la) * HDIM + lkq * 8;
  const int crow = lkq * 4;
  for (int t = 0; t < T_STEPS; t++){
    // ---- MFMA phase: gates = h @ Whh^T, split K into two halves (VGPR budget) ----
    f32x4 acc[4][4] = {};               // [g][nt]
#pragma unroll
    for (int kh = 0; kh < 2; kh++){
      bf16x8 a[8];
#pragma unroll
      for (int k = 0; k < 8; k++)
        a[k] = *(const bf16x8*)(hL + la * 512 + ((((kh * 8 + k) * 4 + lkq) ^ (la & 7)) << 3));
      bf16x8 bb[2][8];
#pragma unroll
      for (int k = 0; k < 8; k++)
        bb[0][k] = *(const bf16x8*)(Bbase + (kh * 8 + k) * 32);
#pragma unroll
      for (int it = 0; it < 16; it++){
        const int g = it >> 2, nt = it & 3;
        if (it + 1 < 16){
          const int g2 = (it + 1) >> 2, nt2 = (it + 1) & 3;
#pragma unroll
          for (int k = 0; k < 8; k++)
            bb[(it + 1) & 1][k] = *(const bf16x8*)(Bbase
                + (size_t)(g2 * 512 + nt2 * 16) * HDIM + (kh * 8 + k) * 32);
        }
#pragma unroll
        for (int k = 0; k < 8; k++)
          acc[g][nt] = __builtin_amdgcn_mfma_f32_16x16x32_bf16(a[k], bb[it & 1][k], acc[g][nt], 0, 0, 0);
      }
    }
    __syncthreads();   // all waves done reading hL
    // ---- cell phase (lane-local): xw loads batched by compiler within phase ----
    const int do_res = (t >= 2) && (t % 3 == 0);
    const unsigned short* xp = XW + (size_t)t * BATCH * G4 + (size_t)(r0 + crow) * G4 + w * 64 + la;
    unsigned short* hsr = hs + (size_t)t * BATCH * HDIM;
    unsigned short* csr = cs + (size_t)t * BATCH * HDIM;
#pragma unroll
    for (int nt = 0; nt < 4; nt++){
      unsigned short hyb[4], cyb[4];
#pragma unroll
      for (int j = 0; j < 4; j++){
        float gi = acc[0][nt][j] + b2f(xp[(size_t)j * G4 + 0 * 512 + nt * 16]);
        float gf = acc[1][nt][j] + b2f(xp[(size_t)j * G4 + 1 * 512 + nt * 16]);
        float gg = acc[2][nt][j] + b2f(xp[(size_t)j * G4 + 2 * 512 + nt * 16]);
        float go = acc[3][nt][j] + b2f(xp[(size_t)j * G4 + 3 * 512 + nt * 16]);
        float cy = sigm(gf) * cx[nt][j] + sigm(gi) * tanhf(gg);
        float hy = sigm(go) * tanhf(cy);
        hyb[j] = f2b(hy); cyb[j] = f2b(cy);
        const int row = crow + j, col = w * 64 + nt * 16 + la;
        size_t p = (size_t)(r0 + row) * HDIM + col;
        hsr[p] = hyb[j]; csr[p] = cyb[j];
        float hn = hy, cn = cy;
        if (do_res){
          unsigned h2 = hm2h[nt][j >> 1], c2 = hm2c[nt][j >> 1];
          unsigned short hh = (j & 1) ? (unsigned short)(h2 >> 16) : (unsigned short)(h2 & 0xffffu);
          unsigned short ch = (j & 1) ? (unsigned short)(c2 >> 16) : (unsigned short)(c2 & 0xffffu);
          hn += b2f(hh); cn += b2f(ch);
        }
        cx[nt][j] = cn;
        hL[row * 512 + ((((col >> 3) ^ (row & 7)) << 3) | (col & 7))] = f2b(hn);
      }
      hm2h[nt][0] = hm1h[nt][0]; hm2h[nt][1] = hm1h[nt][1];
      hm2c[nt][0] = hm1c[nt][0]; hm2c[nt][1] = hm1c[nt][1];
      hm1h[nt][0] = (unsigned)hyb[0] | ((unsigned)hyb[1] << 16);
      hm1h[nt][1] = (unsigned)hyb[2] | ((unsigned)hyb[3] << 16);
      hm1c[nt][0] = (unsigned)cyb[0] | ((unsigned)cyb[1] << 16);
      hm1c[nt][1] = (unsigned)cyb[2] | ((unsigned)cyb[3] << 16);
    }
    __syncthreads();   // hL(t) fully written before next step's reads
  }
}

// ---------------- GEMM 2: packed output projection, A gathered via rmap (round-7) ----
__global__ __launch_bounds__(256) void k_gemm_out(const unsigned short* __restrict__ hs,
                                                  const unsigned short* __restrict__ cs,
                                                  const unsigned short* __restrict__ Wo,
                                                  const float* __restrict__ bout,
                                                  const int* __restrict__ meta,
                                                  const int* __restrict__ rmap,
                                                  float* __restrict__ out){
  int ntot = meta[0];
  int row0 = blockIdx.x * 128, col0 = blockIdx.y * 128;
  if (row0 >= ntot) return;
  __shared__ unsigned short As[128 * 64], Bs[128 * 64];
  const int tid = threadIdx.x, w = tid >> 6, l = tid & 63;
  const int la = l & 15, lkq = l >> 4;
  const int sr = l >> 3, ss = (l & 7) ^ sr;
  const int wr = (w >> 1) * 64, wc = (w & 1) * 64;
  int srow[4];
#pragma unroll
  for (int i = 0; i < 4; i++){
    int rr = rmap[row0 + w * 32 + sr + i * 8];
    srow[i] = rr < 0 ? 0 : rr;
  }
  const unsigned short* gB = Wo + (size_t)(col0 + w * 32 + sr) * 1024 + ss * 8;
  unsigned short* lA = As + (w * 32) * 64;
  unsigned short* lB = Bs + (w * 32) * 64;
  f32x4 acc[4][4] = {};
  for (int k0 = 0; k0 < 1024; k0 += 64){
#pragma unroll
    for (int i = 0; i < 4; i++){
      const unsigned short* srcA = (k0 < 512)
          ? hs + (size_t)srow[i] * 512 + k0 + ss * 8
          : cs + (size_t)srow[i] * 512 + (k0 - 512) + ss * 8;
      gload_lds16(srcA, lA + i * 8 * 64);
      gload_lds16(gB + (size_t)i * 8 * 1024 + k0, lB + i * 8 * 64);
    }
    __syncthreads();
#pragma unroll
    for (int kk = 0; kk < 2; kk++){
      bf16x8 a[4], b[4];
#pragma unroll
      for (int i = 0; i < 4; i++){
        int r = wr + i * 16 + la;
        a[i] = *(const bf16x8*)(As + r * 64 + (((kk * 4 + lkq) ^ (r & 7)) << 3));
      }
#pragma unroll
      for (int i = 0; i < 4; i++){
        int r = wc + i * 16 + la;
        b[i] = *(const bf16x8*)(Bs + r * 64 + (((kk * 4 + lkq) ^ (r & 7)) << 3));
      }
#pragma unroll
      for (int mi = 0; mi < 4; mi++)
#pragma unroll
        for (int ni = 0; ni < 4; ni++)
          acc[mi][ni] = __builtin_amdgcn_mfma_f32_16x16x32_bf16(a[mi], b[ni], acc[mi][ni], 0, 0, 0);
    }
    __syncthreads();
  }
  int r4 = (l >> 4) * 4;
#pragma unroll
  for (int ni = 0; ni < 4; ni++){
    int col = col0 + wc + ni * 16 + la;
    if (col >= VOCAB) continue;
    float bias = bout[col];
#pragma unroll
    for (int mi = 0; mi < 4; mi++)
#pragma unroll
      for (int j = 0; j < 4; j++){
        int row = row0 + wr + mi * 16 + r4 + j;
        if (row < ntot) out[(size_t)row * VOCAB + col] = acc[mi][ni][j] + bias;
      }
  }
}

extern "C" void kernel_launch(void* const* d_in, const int* in_sizes, int n_in,
                              void* d_out, int out_size, void* d_ws, size_t ws_size,
                              hipStream_t stream){
  const float* img   = (const float*)d_in[0];
  const float* txt   = (const float*)d_in[1];
  const float* h0    = (const float*)d_in[2];
  const float* c0    = (const float*)d_in[3];
  const float* emb   = (const float*)d_in[4];
  const float* W_ih  = (const float*)d_in[5];
  const float* W_hh  = (const float*)d_in[6];
  const float* b_ih  = (const float*)d_in[7];
  const float* b_hh  = (const float*)d_in[8];
  const float* W_out = (const float*)d_in[9];
  const float* b_out = (const float*)d_in[10];
  const int* answer  = (const int*)d_in[11];
  const int* lengths = (const int*)d_in[12];
  float* out = (float*)d_out;

  char* ws = (char*)d_ws;
  size_t off = 0;
  auto alloc = [&](size_t bytes) -> void* {
    void* p = ws + off; off += (bytes + 255) & ~(size_t)255; return p;
  };
  unsigned short* Wih_b = (unsigned short*)alloc((size_t)G4 * EDIM * 2);
  unsigned short* Whh_b = (unsigned short*)alloc((size_t)G4 * HDIM * 2);
  unsigned short* Wo_b  = (unsigned short*)alloc((size_t)VPAD * 1024 * 2);
  unsigned short* xs    = (unsigned short*)alloc((size_t)T_STEPS * BATCH * EDIM * 2);
  unsigned short* XW    = (unsigned short*)alloc((size_t)T_STEPS * BATCH * G4 * 2);
  unsigned short* hs    = (unsigned short*)alloc((size_t)T_STEPS * BATCH * HDIM * 2);
  unsigned short* cs    = (unsigned short*)alloc((size_t)T_STEPS * BATCH * HDIM * 2);
  int* bsz  = (int*)alloc(T_STEPS * 4);
  int* roff = (int*)alloc(T_STEPS * 4);
  int* meta = (int*)alloc(256);
  int* rmap = (int*)alloc(T_STEPS * BATCH * 4);

  k_cvt_w<<<(2 * G4 * EDIM + 255) / 256, 256, 0, stream>>>(W_ih, W_hh, Wih_b, Whh_b);
  k_cvt_wout<<<(VPAD * 1024 + 255) / 256, 256, 0, stream>>>(W_out, Wo_b);
  k_build_xs<<<(T_STEPS * BATCH * EDIM + 255) / 256, 256, 0, stream>>>(img, txt, emb, answer, xs);
  k_lens<<<1, 64, 0, stream>>>(lengths, bsz, roff, meta, rmap);

  k_gemm_xw<<<dim3(T_STEPS * BATCH / 128, G4 / 128), 256, 0, stream>>>(xs, Wih_b, b_ih, b_hh, XW);

  k_lstm_chain<<<dim3(BATCH / 16), 512, 0, stream>>>(XW, Whh_b, h0, c0, hs, cs);

  k_gemm_out<<<dim3(T_STEPS * BATCH / 128, VPAD / 128), 256, 0, stream>>>(hs, cs, Wo_b, b_out, meta, rmap, out);
}

// Round 10
// 354.544 us; speedup vs baseline: 7.5788x; 7.5788x over previous
//
#include <hip/hip_runtime.h>
#include <hip/hip_bf16.h>

#define T_STEPS 32
#define BATCH 256
#define EDIM 512
#define HDIM 512
#define G4 2048       // 4*H
#define VOCAB 3000
#define VPAD 3072

typedef short bf16x8 __attribute__((ext_vector_type(8)));
typedef float f32x4 __attribute__((ext_vector_type(4)));

__device__ __forceinline__ unsigned short f2b(float f){
  union { float f; unsigned int u; } x; x.f = f;
  unsigned int u = x.u;
  unsigned int r = (u + 0x7fffu + ((u >> 16) & 1u)) >> 16;
  return (unsigned short)r;
}
__device__ __forceinline__ float b2f(unsigned short h){
  union { unsigned int u; float f; } x; x.u = ((unsigned int)h) << 16;
  return x.f;
}
__device__ __forceinline__ float sigm(float x){ return 1.0f / (1.0f + expf(-x)); }

__device__ __forceinline__ void gload_lds16(const unsigned short* g, unsigned short* l){
  __builtin_amdgcn_global_load_lds(
      (const __attribute__((address_space(1))) unsigned int*)g,
      (__attribute__((address_space(3))) unsigned int*)l, 16, 0, 0);
}

// ---------------- small prep kernels ----------------

__global__ void k_cvt_w(const float* __restrict__ wih, const float* __restrict__ whh,
                        unsigned short* __restrict__ o_ih, unsigned short* __restrict__ o_hh){
  int i = blockIdx.x * blockDim.x + threadIdx.x;   // over 2 * G4*512
  int n1 = G4 * EDIM;
  if (i < n1) o_ih[i] = f2b(wih[i]);
  else { int j = i - n1; if (j < G4 * HDIM) o_hh[j] = f2b(whh[j]); }
}

__global__ void k_cvt_wout(const float* __restrict__ in, unsigned short* __restrict__ out){
  int i = blockIdx.x * blockDim.x + threadIdx.x; // over VPAD*1024
  if (i >= VPAD * 1024) return;
  int r = i >> 10, c = i & 1023;
  float v = (r < VOCAB) ? in[r * 1024 + c] : 0.0f;
  out[i] = f2b(v);
}

__global__ void k_build_xs(const float* __restrict__ img, const float* __restrict__ txt,
                           const float* __restrict__ emb, const int* __restrict__ ans,
                           unsigned short* __restrict__ xs){
  int i = blockIdx.x * blockDim.x + threadIdx.x; // over T*B*E
  if (i >= T_STEPS * BATCH * EDIM) return;
  int e = i & (EDIM - 1);
  int r = i >> 9;              // t*B + b
  int t = r >> 8, b = r & 255;
  float v;
  if (t == 0) v = (e < 256) ? img[b * 256 + e] : txt[b * 256 + (e - 256)];
  else { int tok = ans[b * T_STEPS + (t - 1)]; v = emb[(size_t)tok * EDIM + e]; }
  xs[i] = f2b(v);
}

__global__ void k_init_carry(const float* __restrict__ h0, const float* __restrict__ c0,
                             unsigned short* __restrict__ hx, float* __restrict__ cx){
  int i = blockIdx.x * blockDim.x + threadIdx.x;
  if (i < BATCH * HDIM){ hx[i] = f2b(h0[i]); cx[i] = c0[i]; }
}

// batch_sizes, packed row offsets, total rows, dest->src row map
__global__ void k_lens(const int* __restrict__ lengths, int* __restrict__ bs,
                       int* __restrict__ roff, int* __restrict__ meta,
                       int* __restrict__ rmap){
  __shared__ int s[T_STEPS];
  __shared__ int sroff[T_STEPS + 1];
  int t = threadIdx.x; // 64 threads
  if (t < T_STEPS){
    int c = 0;
    for (int i = 0; i < BATCH; i++) c += (lengths[i] > t) ? 1 : 0;
    s[t] = c; bs[t] = c;
  }
  __syncthreads();
  if (t == 0){
    int acc = 0;
    for (int u = 0; u < T_STEPS; u++){ sroff[u] = acc; roff[u] = acc; acc += s[u]; }
    sroff[T_STEPS] = acc;
    meta[0] = acc;
  }
  __syncthreads();
  int ntot = sroff[T_STEPS];
  for (int r = t; r < T_STEPS * BATCH; r += 64){
    int tt = r >> 8, b = r & 255;
    if (b < s[tt]) rmap[sroff[tt] + b] = r;
  }
  for (int r = ntot + t; r < T_STEPS * BATCH; r += 64) rmap[r] = -1;
}

// ---------------- staged 128x128 GEMM core, BK=64, XOR-swizzled LDS ----------------
template<int K>
__device__ __forceinline__ void gemm_tile(const unsigned short* __restrict__ A,
                                          const unsigned short* __restrict__ B,
                                          int row0, int col0,
                                          unsigned short* As, unsigned short* Bs,
                                          f32x4 acc[4][4]){
  const int tid = threadIdx.x, w = tid >> 6, l = tid & 63;
  const int la = l & 15, lkq = l >> 4;
  const int sr = l >> 3;            // row within 8-row staging group
  const int ss = (l & 7) ^ sr;      // pre-swizzled source slot
  const int wr = (w >> 1) * 64, wc = (w & 1) * 64;
  const unsigned short* gA = A + (size_t)(row0 + w * 32 + sr) * K + ss * 8;
  const unsigned short* gB = B + (size_t)(col0 + w * 32 + sr) * K + ss * 8;
  unsigned short* lA = As + (w * 32) * 64;
  unsigned short* lB = Bs + (w * 32) * 64;
  for (int k0 = 0; k0 < K; k0 += 64){
#pragma unroll
    for (int i = 0; i < 4; i++){
      gload_lds16(gA + (size_t)i * 8 * K + k0, lA + i * 8 * 64);
      gload_lds16(gB + (size_t)i * 8 * K + k0, lB + i * 8 * 64);
    }
    __syncthreads();
#pragma unroll
    for (int kk = 0; kk < 2; kk++){
      bf16x8 a[4], b[4];
#pragma unroll
      for (int i = 0; i < 4; i++){
        int r = wr + i * 16 + la;
        a[i] = *(const bf16x8*)(As + r * 64 + (((kk * 4 + lkq) ^ (r & 7)) << 3));
      }
#pragma unroll
      for (int i = 0; i < 4; i++){
        int r = wc + i * 16 + la;
        b[i] = *(const bf16x8*)(Bs + r * 64 + (((kk * 4 + lkq) ^ (r & 7)) << 3));
      }
#pragma unroll
      for (int mi = 0; mi < 4; mi++)
#pragma unroll
        for (int ni = 0; ni < 4; ni++)
          acc[mi][ni] = __builtin_amdgcn_mfma_f32_16x16x32_bf16(a[mi], b[ni], acc[mi][ni], 0, 0, 0);
    }
    __syncthreads();
  }
}

// ---------------- GEMM 1: XW = xs @ W_ih^T + b_ih + b_hh (bf16 out) ----------------
// 1D grid 1024 = 8 XCDs x 128; each XCD owns 2 of 16 col-panels (W_ih slice L2-resident)
__global__ __launch_bounds__(256) void k_gemm_xw(const unsigned short* __restrict__ A,
                                                 const unsigned short* __restrict__ W,
                                                 const float* __restrict__ bih,
                                                 const float* __restrict__ bhh,
                                                 unsigned short* __restrict__ C){
  __shared__ unsigned short As[128 * 64], Bs[128 * 64];
  int bid = blockIdx.x;
  int xcd = bid & 7, idx = bid >> 3;          // idx 0..127
  int by = xcd * 2 + (idx & 1);               // 16 col-panels, 2 per XCD
  int bx = idx >> 1;                          // 64 row-blocks
  int row0 = bx * 128, col0 = by * 128;
  f32x4 acc[4][4] = {};
  gemm_tile<EDIM>(A, W, row0, col0, As, Bs, acc);
  int tid = threadIdx.x, w = tid >> 6, l = tid & 63;
  int la = l & 15, r4 = (l >> 4) * 4;
  int wr = (w >> 1) * 64, wc = (w & 1) * 64;
#pragma unroll
  for (int ni = 0; ni < 4; ni++){
    int col = col0 + wc + ni * 16 + la;
    float bias = bih[col] + bhh[col];
#pragma unroll
    for (int mi = 0; mi < 4; mi++)
#pragma unroll
      for (int j = 0; j < 4; j++){
        int row = row0 + wr + mi * 16 + r4 + j;
        C[(size_t)row * G4 + col] = f2b(acc[mi][ni][j] + bias);
      }
  }
}

// ---------------- fused recurrent step: 512 blocks (16 rows x 16 hcols), wave=gate ----
// All 16 Whh B-fragments hoisted into registers -> one batched latency exposure.
__global__ __launch_bounds__(256, 2) void k_lstm_step(
    const unsigned short* __restrict__ XWt,
    const unsigned short* __restrict__ Whh,
    const unsigned short* __restrict__ hin,
    unsigned short* __restrict__ hout,
    float* __restrict__ cxio,
    unsigned short* __restrict__ hs_t,
    unsigned short* __restrict__ cs_t,
    const unsigned short* __restrict__ hs_m2,
    const unsigned short* __restrict__ cs_m2,
    int do_res){
  __shared__ unsigned short hA[16 * 512];   // swizzled h tile
  __shared__ float gbuf[4][16][17];
  const int w = threadIdx.x >> 6, l = threadIdx.x & 63;
  const int la = l & 15, lkq = l >> 4;
  const int row0 = blockIdx.x * 16;
  const int hc0  = blockIdx.y * 16;
  // stage h tile: wave w stages rows {w, 4+w, 8+w, 12+w}; source slot pre-swizzled
#pragma unroll
  for (int i = 0; i < 4; i++){
    int r = i * 4 + w;
    gload_lds16(hin + (size_t)(row0 + r) * HDIM + ((l ^ (r & 7)) << 3), hA + r * 512);
  }
  // hoist ALL 16 Whh B-fragments (independent, issued back-to-back)
  const unsigned short* Bp = Whh + (size_t)(w * HDIM + hc0 + la) * HDIM + lkq * 8;
  bf16x8 b[16];
#pragma unroll
  for (int kk = 0; kk < 16; kk++) b[kk] = *(const bf16x8*)(Bp + kk * 32);
  // hoist XW (consumed after MFMA loop)
  const int r4 = lkq * 4;
  float x[4];
#pragma unroll
  for (int j = 0; j < 4; j++)
    x[j] = b2f(XWt[(size_t)(row0 + r4 + j) * G4 + w * HDIM + hc0 + la]);
  __syncthreads();
  f32x4 acc = {};
#pragma unroll
  for (int kk = 0; kk < 16; kk++){
    bf16x8 a = *(const bf16x8*)(hA + la * 512 + (((kk * 4 + lkq) ^ (la & 7)) << 3));
    acc = __builtin_amdgcn_mfma_f32_16x16x32_bf16(a, b[kk], acc, 0, 0, 0);
  }
#pragma unroll
  for (int j = 0; j < 4; j++) gbuf[w][r4 + j][la] = acc[j] + x[j];
  __syncthreads();
  {
    int r = threadIdx.x >> 4, c = threadIdx.x & 15;
    size_t p = (size_t)(row0 + r) * HDIM + hc0 + c;
    float gi = gbuf[0][r][c], gf = gbuf[1][r][c], gg = gbuf[2][r][c], go = gbuf[3][r][c];
    float cprev = cxio[p];
    float cy = sigm(gf) * cprev + sigm(gi) * tanhf(gg);
    float hy = sigm(go) * tanhf(cy);
    hs_t[p] = f2b(hy);
    cs_t[p] = f2b(cy);
    float hn = hy, cn = cy;
    if (do_res){ hn += b2f(hs_m2[p]); cn += b2f(cs_m2[p]); }
    hout[p] = f2b(hn);
    cxio[p] = cn;
  }
}

// ---------------- GEMM 2: packed output projection, A gathered via rmap ----------------
// 1D grid 1536 = 8 XCDs x 192; each XCD owns 3 of 24 col-panels (Wo slice 768KB, L2-resident)
__global__ __launch_bounds__(256) void k_gemm_out(const unsigned short* __restrict__ hs,
                                                  const unsigned short* __restrict__ cs,
                                                  const unsigned short* __restrict__ Wo,
                                                  const float* __restrict__ bout,
                                                  const int* __restrict__ meta,
                                                  const int* __restrict__ rmap,
                                                  float* __restrict__ out){
  int ntot = meta[0];
  int bid = blockIdx.x;
  int xcd = bid & 7, idx = bid >> 3;          // idx 0..191
  int by = xcd * 3 + (idx % 3);               // 24 col-panels, 3 per XCD
  int bx = idx / 3;                           // 64 row-blocks
  int row0 = bx * 128, col0 = by * 128;
  if (row0 >= ntot) return;
  __shared__ unsigned short As[128 * 64], Bs[128 * 64];
  const int tid = threadIdx.x, w = tid >> 6, l = tid & 63;
  const int la = l & 15, lkq = l >> 4;
  const int sr = l >> 3, ss = (l & 7) ^ sr;
  const int wr = (w >> 1) * 64, wc = (w & 1) * 64;
  int srow[4];
#pragma unroll
  for (int i = 0; i < 4; i++){
    int rr = rmap[row0 + w * 32 + sr + i * 8];
    srow[i] = rr < 0 ? 0 : rr;
  }
  const unsigned short* gB = Wo + (size_t)(col0 + w * 32 + sr) * 1024 + ss * 8;
  unsigned short* lA = As + (w * 32) * 64;
  unsigned short* lB = Bs + (w * 32) * 64;
  f32x4 acc[4][4] = {};
  for (int k0 = 0; k0 < 1024; k0 += 64){
#pragma unroll
    for (int i = 0; i < 4; i++){
      const unsigned short* srcA = (k0 < 512)
          ? hs + (size_t)srow[i] * 512 + k0 + ss * 8
          : cs + (size_t)srow[i] * 512 + (k0 - 512) + ss * 8;
      gload_lds16(srcA, lA + i * 8 * 64);
      gload_lds16(gB + (size_t)i * 8 * 1024 + k0, lB + i * 8 * 64);
    }
    __syncthreads();
#pragma unroll
    for (int kk = 0; kk < 2; kk++){
      bf16x8 a[4], b[4];
#pragma unroll
      for (int i = 0; i < 4; i++){
        int r = wr + i * 16 + la;
        a[i] = *(const bf16x8*)(As + r * 64 + (((kk * 4 + lkq) ^ (r & 7)) << 3));
      }
#pragma unroll
      for (int i = 0; i < 4; i++){
        int r = wc + i * 16 + la;
        b[i] = *(const bf16x8*)(Bs + r * 64 + (((kk * 4 + lkq) ^ (r & 7)) << 3));
      }
#pragma unroll
      for (int mi = 0; mi < 4; mi++)
#pragma unroll
        for (int ni = 0; ni < 4; ni++)
          acc[mi][ni] = __builtin_amdgcn_mfma_f32_16x16x32_bf16(a[mi], b[ni], acc[mi][ni], 0, 0, 0);
    }
    __syncthreads();
  }
  int r4 = (l >> 4) * 4;
#pragma unroll
  for (int ni = 0; ni < 4; ni++){
    int col = col0 + wc + ni * 16 + la;
    if (col >= VOCAB) continue;
    float bias = bout[col];
#pragma unroll
    for (int mi = 0; mi < 4; mi++)
#pragma unroll
      for (int j = 0; j < 4; j++){
        int row = row0 + wr + mi * 16 + r4 + j;
        if (row < ntot) out[(size_t)row * VOCAB + col] = acc[mi][ni][j] + bias;
      }
  }
}

extern "C" void kernel_launch(void* const* d_in, const int* in_sizes, int n_in,
                              void* d_out, int out_size, void* d_ws, size_t ws_size,
                              hipStream_t stream){
  const float* img   = (const float*)d_in[0];
  const float* txt   = (const float*)d_in[1];
  const float* h0    = (const float*)d_in[2];
  const float* c0    = (const float*)d_in[3];
  const float* emb   = (const float*)d_in[4];
  const float* W_ih  = (const float*)d_in[5];
  const float* W_hh  = (const float*)d_in[6];
  const float* b_ih  = (const float*)d_in[7];
  const float* b_hh  = (const float*)d_in[8];
  const float* W_out = (const float*)d_in[9];
  const float* b_out = (const float*)d_in[10];
  const int* answer  = (const int*)d_in[11];
  const int* lengths = (const int*)d_in[12];
  float* out = (float*)d_out;

  char* ws = (char*)d_ws;
  size_t off = 0;
  auto alloc = [&](size_t bytes) -> void* {
    void* p = ws + off; off += (bytes + 255) & ~(size_t)255; return p;
  };
  unsigned short* Wih_b = (unsigned short*)alloc((size_t)G4 * EDIM * 2);
  unsigned short* Whh_b = (unsigned short*)alloc((size_t)G4 * HDIM * 2);
  unsigned short* Wo_b  = (unsigned short*)alloc((size_t)VPAD * 1024 * 2);
  unsigned short* xs    = (unsigned short*)alloc((size_t)T_STEPS * BATCH * EDIM * 2);
  unsigned short* XW    = (unsigned short*)alloc((size_t)T_STEPS * BATCH * G4 * 2);
  unsigned short* hs    = (unsigned short*)alloc((size_t)T_STEPS * BATCH * HDIM * 2);
  unsigned short* cs    = (unsigned short*)alloc((size_t)T_STEPS * BATCH * HDIM * 2);
  unsigned short* hxA   = (unsigned short*)alloc((size_t)BATCH * HDIM * 2);
  unsigned short* hxB   = (unsigned short*)alloc((size_t)BATCH * HDIM * 2);
  float* cx             = (float*)alloc((size_t)BATCH * HDIM * 4);
  int* bsz  = (int*)alloc(T_STEPS * 4);
  int* roff = (int*)alloc(T_STEPS * 4);
  int* meta = (int*)alloc(256);
  int* rmap = (int*)alloc(T_STEPS * BATCH * 4);

  k_cvt_w<<<(2 * G4 * EDIM + 255) / 256, 256, 0, stream>>>(W_ih, W_hh, Wih_b, Whh_b);
  k_cvt_wout<<<(VPAD * 1024 + 255) / 256, 256, 0, stream>>>(W_out, Wo_b);
  k_build_xs<<<(T_STEPS * BATCH * EDIM + 255) / 256, 256, 0, stream>>>(img, txt, emb, answer, xs);
  k_init_carry<<<(BATCH * HDIM + 255) / 256, 256, 0, stream>>>(h0, c0, hxA, cx);
  k_lens<<<1, 64, 0, stream>>>(lengths, bsz, roff, meta, rmap);

  k_gemm_xw<<<dim3(1024), 256, 0, stream>>>(xs, Wih_b, b_ih, b_hh, XW);

  unsigned short* hbuf[2] = { hxA, hxB };
  for (int t = 0; t < T_STEPS; t++){
    int do_res = (t >= 2 && (t % 3) == 0) ? 1 : 0;
    int tm2 = (t >= 2) ? (t - 2) : 0;
    k_lstm_step<<<dim3(BATCH / 16, HDIM / 16), 256, 0, stream>>>(
        XW + (size_t)t * BATCH * G4, Whh_b, hbuf[t & 1], hbuf[(t + 1) & 1], cx,
        hs + (size_t)t * BATCH * HDIM, cs + (size_t)t * BATCH * HDIM,
        hs + (size_t)tm2 * BATCH * HDIM, cs + (size_t)tm2 * BATCH * HDIM, do_res);
  }

  k_gemm_out<<<dim3(1536), 256, 0, stream>>>(hs, cs, Wo_b, b_out, meta, rmap, out);
}

// Round 11
// 352.956 us; speedup vs baseline: 7.6129x; 1.0045x over previous
//
#include <hip/hip_runtime.h>
#include <hip/hip_bf16.h>

#define T_STEPS 32
#define BATCH 256
#define EDIM 512
#define HDIM 512
#define G4 2048       // 4*H
#define VOCAB 3000
#define VPAD 3072

typedef short bf16x8 __attribute__((ext_vector_type(8)));
typedef float f32x4 __attribute__((ext_vector_type(4)));

__device__ __forceinline__ unsigned short f2b(float f){
  union { float f; unsigned int u; } x; x.f = f;
  unsigned int u = x.u;
  unsigned int r = (u + 0x7fffu + ((u >> 16) & 1u)) >> 16;
  return (unsigned short)r;
}
__device__ __forceinline__ float b2f(unsigned short h){
  union { unsigned int u; float f; } x; x.u = ((unsigned int)h) << 16;
  return x.f;
}
__device__ __forceinline__ float sigm(float x){ return 1.0f / (1.0f + expf(-x)); }

__device__ __forceinline__ void gload_lds16(const unsigned short* g, unsigned short* l){
  __builtin_amdgcn_global_load_lds(
      (const __attribute__((address_space(1))) unsigned int*)g,
      (__attribute__((address_space(3))) unsigned int*)l, 16, 0, 0);
}

#define SB0 __builtin_amdgcn_sched_barrier(0)

// ---------------- small prep kernels ----------------

__global__ void k_cvt_w(const float* __restrict__ wih, const float* __restrict__ whh,
                        unsigned short* __restrict__ o_ih, unsigned short* __restrict__ o_hh){
  int i = blockIdx.x * blockDim.x + threadIdx.x;   // over 2 * G4*512
  int n1 = G4 * EDIM;
  if (i < n1) o_ih[i] = f2b(wih[i]);
  else { int j = i - n1; if (j < G4 * HDIM) o_hh[j] = f2b(whh[j]); }
}

__global__ void k_cvt_wout(const float* __restrict__ in, unsigned short* __restrict__ out){
  int i = blockIdx.x * blockDim.x + threadIdx.x; // over VPAD*1024
  if (i >= VPAD * 1024) return;
  int r = i >> 10, c = i & 1023;
  float v = (r < VOCAB) ? in[r * 1024 + c] : 0.0f;
  out[i] = f2b(v);
}

__global__ void k_build_xs(const float* __restrict__ img, const float* __restrict__ txt,
                           const float* __restrict__ emb, const int* __restrict__ ans,
                           unsigned short* __restrict__ xs){
  int i = blockIdx.x * blockDim.x + threadIdx.x; // over T*B*E
  if (i >= T_STEPS * BATCH * EDIM) return;
  int e = i & (EDIM - 1);
  int r = i >> 9;              // t*B + b
  int t = r >> 8, b = r & 255;
  float v;
  if (t == 0) v = (e < 256) ? img[b * 256 + e] : txt[b * 256 + (e - 256)];
  else { int tok = ans[b * T_STEPS + (t - 1)]; v = emb[(size_t)tok * EDIM + e]; }
  xs[i] = f2b(v);
}

__global__ void k_init_carry(const float* __restrict__ h0, const float* __restrict__ c0,
                             unsigned short* __restrict__ hx, float* __restrict__ cx){
  int i = blockIdx.x * blockDim.x + threadIdx.x;
  if (i < BATCH * HDIM){ hx[i] = f2b(h0[i]); cx[i] = c0[i]; }
}

// batch_sizes, packed row offsets, total rows, dest->src row map
__global__ void k_lens(const int* __restrict__ lengths, int* __restrict__ bs,
                       int* __restrict__ roff, int* __restrict__ meta,
                       int* __restrict__ rmap){
  __shared__ int s[T_STEPS];
  __shared__ int sroff[T_STEPS + 1];
  int t = threadIdx.x; // 64 threads
  if (t < T_STEPS){
    int c = 0;
    for (int i = 0; i < BATCH; i++) c += (lengths[i] > t) ? 1 : 0;
    s[t] = c; bs[t] = c;
  }
  __syncthreads();
  if (t == 0){
    int acc = 0;
    for (int u = 0; u < T_STEPS; u++){ sroff[u] = acc; roff[u] = acc; acc += s[u]; }
    sroff[T_STEPS] = acc;
    meta[0] = acc;
  }
  __syncthreads();
  int ntot = sroff[T_STEPS];
  for (int r = t; r < T_STEPS * BATCH; r += 64){
    int tt = r >> 8, b = r & 255;
    if (b < s[tt]) rmap[sroff[tt] + b] = r;
  }
  for (int r = ntot + t; r < T_STEPS * BATCH; r += 64) rmap[r] = -1;
}

// ---------------- staged 128x128 GEMM core, BK=64, XOR-swizzled LDS ----------------
template<int K>
__device__ __forceinline__ void gemm_tile(const unsigned short* __restrict__ A,
                                          const unsigned short* __restrict__ B,
                                          int row0, int col0,
                                          unsigned short* As, unsigned short* Bs,
                                          f32x4 acc[4][4]){
  const int tid = threadIdx.x, w = tid >> 6, l = tid & 63;
  const int la = l & 15, lkq = l >> 4;
  const int sr = l >> 3;            // row within 8-row staging group
  const int ss = (l & 7) ^ sr;      // pre-swizzled source slot
  const int wr = (w >> 1) * 64, wc = (w & 1) * 64;
  const unsigned short* gA = A + (size_t)(row0 + w * 32 + sr) * K + ss * 8;
  const unsigned short* gB = B + (size_t)(col0 + w * 32 + sr) * K + ss * 8;
  unsigned short* lA = As + (w * 32) * 64;
  unsigned short* lB = Bs + (w * 32) * 64;
  for (int k0 = 0; k0 < K; k0 += 64){
#pragma unroll
    for (int i = 0; i < 4; i++){
      gload_lds16(gA + (size_t)i * 8 * K + k0, lA + i * 8 * 64);
      gload_lds16(gB + (size_t)i * 8 * K + k0, lB + i * 8 * 64);
    }
    __syncthreads();
#pragma unroll
    for (int kk = 0; kk < 2; kk++){
      bf16x8 a[4], b[4];
#pragma unroll
      for (int i = 0; i < 4; i++){
        int r = wr + i * 16 + la;
        a[i] = *(const bf16x8*)(As + r * 64 + (((kk * 4 + lkq) ^ (r & 7)) << 3));
      }
#pragma unroll
      for (int i = 0; i < 4; i++){
        int r = wc + i * 16 + la;
        b[i] = *(const bf16x8*)(Bs + r * 64 + (((kk * 4 + lkq) ^ (r & 7)) << 3));
      }
#pragma unroll
      for (int mi = 0; mi < 4; mi++)
#pragma unroll
        for (int ni = 0; ni < 4; ni++)
          acc[mi][ni] = __builtin_amdgcn_mfma_f32_16x16x32_bf16(a[mi], b[ni], acc[mi][ni], 0, 0, 0);
    }
    __syncthreads();
  }
}

// ---------------- GEMM 1: XW = xs @ W_ih^T + b_ih + b_hh (bf16 out) ----------------
__global__ __launch_bounds__(256) void k_gemm_xw(const unsigned short* __restrict__ A,
                                                 const unsigned short* __restrict__ W,
                                                 const float* __restrict__ bih,
                                                 const float* __restrict__ bhh,
                                                 unsigned short* __restrict__ C){
  __shared__ unsigned short As[128 * 64], Bs[128 * 64];
  int bid = blockIdx.x;
  int xcd = bid & 7, idx = bid >> 3;          // idx 0..127
  int by = xcd * 2 + (idx & 1);               // 16 col-panels, 2 per XCD
  int bx = idx >> 1;                          // 64 row-blocks
  int row0 = bx * 128, col0 = by * 128;
  f32x4 acc[4][4] = {};
  gemm_tile<EDIM>(A, W, row0, col0, As, Bs, acc);
  int tid = threadIdx.x, w = tid >> 6, l = tid & 63;
  int la = l & 15, r4 = (l >> 4) * 4;
  int wr = (w >> 1) * 64, wc = (w & 1) * 64;
#pragma unroll
  for (int ni = 0; ni < 4; ni++){
    int col = col0 + wc + ni * 16 + la;
    float bias = bih[col] + bhh[col];
#pragma unroll
    for (int mi = 0; mi < 4; mi++)
#pragma unroll
      for (int j = 0; j < 4; j++){
        int row = row0 + wr + mi * 16 + r4 + j;
        C[(size_t)row * G4 + col] = f2b(acc[mi][ni][j] + bias);
      }
  }
}

// ---------------- fused recurrent step: 512 blocks (16 rows x 16 hcols), wave=gate ----
__global__ __launch_bounds__(256, 2) void k_lstm_step(
    const unsigned short* __restrict__ XWt,
    const unsigned short* __restrict__ Whh,
    const unsigned short* __restrict__ hin,
    unsigned short* __restrict__ hout,
    float* __restrict__ cxio,
    unsigned short* __restrict__ hs_t,
    unsigned short* __restrict__ cs_t,
    const unsigned short* __restrict__ hs_m2,
    const unsigned short* __restrict__ cs_m2,
    int do_res){
  __shared__ unsigned short hA[16 * 512];   // swizzled h tile
  __shared__ float gbuf[4][16][17];
  const int w = threadIdx.x >> 6, l = threadIdx.x & 63;
  const int la = l & 15, lkq = l >> 4;
  const int row0 = blockIdx.x * 16;
  const int hc0  = blockIdx.y * 16;
#pragma unroll
  for (int i = 0; i < 4; i++){
    int r = i * 4 + w;
    gload_lds16(hin + (size_t)(row0 + r) * HDIM + ((l ^ (r & 7)) << 3), hA + r * 512);
  }
  const unsigned short* Bp = Whh + (size_t)(w * HDIM + hc0 + la) * HDIM + lkq * 8;
  bf16x8 b[16];
#pragma unroll
  for (int kk = 0; kk < 16; kk++) b[kk] = *(const bf16x8*)(Bp + kk * 32);
  const int r4 = lkq * 4;
  float x[4];
#pragma unroll
  for (int j = 0; j < 4; j++)
    x[j] = b2f(XWt[(size_t)(row0 + r4 + j) * G4 + w * HDIM + hc0 + la]);
  __syncthreads();
  f32x4 acc = {};
#pragma unroll
  for (int kk = 0; kk < 16; kk++){
    bf16x8 a = *(const bf16x8*)(hA + la * 512 + (((kk * 4 + lkq) ^ (la & 7)) << 3));
    acc = __builtin_amdgcn_mfma_f32_16x16x32_bf16(a, b[kk], acc, 0, 0, 0);
  }
#pragma unroll
  for (int j = 0; j < 4; j++) gbuf[w][r4 + j][la] = acc[j] + x[j];
  __syncthreads();
  {
    int r = threadIdx.x >> 4, c = threadIdx.x & 15;
    size_t p = (size_t)(row0 + r) * HDIM + hc0 + c;
    float gi = gbuf[0][r][c], gf = gbuf[1][r][c], gg = gbuf[2][r][c], go = gbuf[3][r][c];
    float cprev = cxio[p];
    float cy = sigm(gf) * cprev + sigm(gi) * tanhf(gg);
    float hy = sigm(go) * tanhf(cy);
    hs_t[p] = f2b(hy);
    cs_t[p] = f2b(cy);
    float hn = hy, cn = cy;
    if (do_res){ hn += b2f(hs_m2[p]); cn += b2f(cs_m2[p]); }
    hout[p] = f2b(hn);
    cxio[p] = cn;
  }
}

// ---------------- GEMM 2: 8-phase pipelined 256x128, 3-slot LDS, counted vmcnt ----------------
// 512 thr = 8 waves (2M x 4N), wave C = 128x32. Per K-tile (BK=64): 2 phases, each
// {ds_read frags || 3 global_load_lds for kt+2 -> barrier -> lgkmcnt(0) -> 16 MFMA ->
//  [phase 2: vmcnt(6)] -> barrier}. Loads span 2 iterations; never drain in-loop.
__global__ __launch_bounds__(512) void k_gemm_out(const unsigned short* __restrict__ hs,
                                                  const unsigned short* __restrict__ cs,
                                                  const unsigned short* __restrict__ Wo,
                                                  const float* __restrict__ bout,
                                                  const int* __restrict__ meta,
                                                  const int* __restrict__ rmap,
                                                  float* __restrict__ out){
  const int ntot = meta[0];
  const int row0 = blockIdx.x * 256, col0 = blockIdx.y * 128;
  if (row0 >= ntot) return;
  __shared__ unsigned short As[3][256 * 64];   // 96 KB
  __shared__ unsigned short Bs[3][128 * 64];   // 48 KB
  const int t = threadIdx.x, w = t >> 6, l = t & 63;
  const int la = l & 15, lkq = l >> 4;
  const int wm = w >> 2, wn = w & 3;
  const int tr = t >> 3, ss = (t & 7) ^ (tr & 7);
  int srowA[4];
#pragma unroll
  for (int p = 0; p < 4; p++){
    int rr = rmap[row0 + p * 64 + tr];
    srowA[p] = rr < 0 ? 0 : rr;
  }
  f32x4 acc[8][2] = {};

#define STG_A(KT2, P) gload_lds16(                                              \
    ((KT2) < 8 ? hs : cs) + (size_t)srowA[P] * 512 + ((KT2) & 7) * 64 + ss * 8, \
    &As[(KT2) % 3][((P) * 64 + w * 8) * 64])
#define STG_B(KT2, Q) gload_lds16(                                              \
    Wo + (size_t)(col0 + (Q) * 64 + tr) * 1024 + (KT2) * 64 + ss * 8,           \
    &Bs[(KT2) % 3][((Q) * 64 + w * 8) * 64])

  // prologue: stage kt=0 and kt=1 (12 loads/thread), wait kt0 (6 stay in flight)
  STG_A(0,0); STG_A(0,1); STG_A(0,2); STG_A(0,3); STG_B(0,0); STG_B(0,1);
  STG_A(1,0); STG_A(1,1); STG_A(1,2); STG_A(1,3); STG_B(1,0); STG_B(1,1);
  SB0;
  asm volatile("s_waitcnt vmcnt(6)" ::: "memory");
  SB0; __builtin_amdgcn_s_barrier(); SB0;

  for (int kt = 0; kt < 16; ++kt){
    const unsigned short* Acur = As[kt % 3];
    const unsigned short* Bcur = Bs[kt % 3];
    const int kt2 = kt + 2;
    const bool st = (kt2 < 16);
    bf16x8 b[2][2];
    // ---- phase 1: B frags + A frags mf0..3; stage A0,A1,B0 of kt+2 ----
    {
#pragma unroll
      for (int nf = 0; nf < 2; nf++){
        int rc = wn * 32 + nf * 16 + la;
#pragma unroll
        for (int kk = 0; kk < 2; kk++)
          b[nf][kk] = *(const bf16x8*)(Bcur + rc * 64 + (((kk * 4 + lkq) ^ (rc & 7)) << 3));
      }
      bf16x8 a[4][2];
#pragma unroll
      for (int m2 = 0; m2 < 4; m2++){
        int rr = wm * 128 + m2 * 16 + la;
#pragma unroll
        for (int kk = 0; kk < 2; kk++)
          a[m2][kk] = *(const bf16x8*)(Acur + rr * 64 + (((kk * 4 + lkq) ^ (rr & 7)) << 3));
      }
      if (st){ STG_A(kt2,0); STG_A(kt2,1); STG_B(kt2,0); }
      SB0; __builtin_amdgcn_s_barrier();
      asm volatile("s_waitcnt lgkmcnt(0)" ::: "memory");
      SB0;
      __builtin_amdgcn_s_setprio(1);
#pragma unroll
      for (int m2 = 0; m2 < 4; m2++)
#pragma unroll
        for (int nf = 0; nf < 2; nf++)
#pragma unroll
          for (int kk = 0; kk < 2; kk++)
            acc[m2][nf] = __builtin_amdgcn_mfma_f32_16x16x32_bf16(a[m2][kk], b[nf][kk], acc[m2][nf], 0, 0, 0);
      __builtin_amdgcn_s_setprio(0);
      SB0; __builtin_amdgcn_s_barrier(); SB0;
    }
    // ---- phase 2: A frags mf4..7; stage A2,A3,B1 of kt+2; counted vmcnt; barrier ----
    {
      bf16x8 a[4][2];
#pragma unroll
      for (int m2 = 0; m2 < 4; m2++){
        int rr = wm * 128 + (4 + m2) * 16 + la;
#pragma unroll
        for (int kk = 0; kk < 2; kk++)
          a[m2][kk] = *(const bf16x8*)(Acur + rr * 64 + (((kk * 4 + lkq) ^ (rr & 7)) << 3));
      }
      if (st){ STG_A(kt2,2); STG_A(kt2,3); STG_B(kt2,1); }
      SB0; __builtin_amdgcn_s_barrier();
      asm volatile("s_waitcnt lgkmcnt(0)" ::: "memory");
      SB0;
      __builtin_amdgcn_s_setprio(1);
#pragma unroll
      for (int m2 = 0; m2 < 4; m2++)
#pragma unroll
        for (int nf = 0; nf < 2; nf++)
#pragma unroll
          for (int kk = 0; kk < 2; kk++)
            acc[4 + m2][nf] = __builtin_amdgcn_mfma_f32_16x16x32_bf16(a[m2][kk], b[nf][kk], acc[4 + m2][nf], 0, 0, 0);
      __builtin_amdgcn_s_setprio(0);
      SB0;
      // ensure kt+1's loads (all waves) visible after the coming barrier;
      // kt+2's 6 loads stay in flight (counted, never 0 until tail)
      if (kt <= 13){ asm volatile("s_waitcnt vmcnt(6)" ::: "memory"); }
      else if (kt == 14){ asm volatile("s_waitcnt vmcnt(0)" ::: "memory"); }
      SB0; __builtin_amdgcn_s_barrier(); SB0;
    }
  }
#undef STG_A
#undef STG_B
  // epilogue
#pragma unroll
  for (int nf = 0; nf < 2; nf++){
    int col = col0 + wn * 32 + nf * 16 + la;
    if (col >= VOCAB) continue;
    float bias = bout[col];
#pragma unroll
    for (int mf = 0; mf < 8; mf++)
#pragma unroll
      for (int j = 0; j < 4; j++){
        int row = row0 + wm * 128 + mf * 16 + lkq * 4 + j;
        if (row < ntot) out[(size_t)row * VOCAB + col] = acc[mf][nf][j] + bias;
      }
  }
}

extern "C" void kernel_launch(void* const* d_in, const int* in_sizes, int n_in,
                              void* d_out, int out_size, void* d_ws, size_t ws_size,
                              hipStream_t stream){
  const float* img   = (const float*)d_in[0];
  const float* txt   = (const float*)d_in[1];
  const float* h0    = (const float*)d_in[2];
  const float* c0    = (const float*)d_in[3];
  const float* emb   = (const float*)d_in[4];
  const float* W_ih  = (const float*)d_in[5];
  const float* W_hh  = (const float*)d_in[6];
  const float* b_ih  = (const float*)d_in[7];
  const float* b_hh  = (const float*)d_in[8];
  const float* W_out = (const float*)d_in[9];
  const float* b_out = (const float*)d_in[10];
  const int* answer  = (const int*)d_in[11];
  const int* lengths = (const int*)d_in[12];
  float* out = (float*)d_out;

  char* ws = (char*)d_ws;
  size_t off = 0;
  auto alloc = [&](size_t bytes) -> void* {
    void* p = ws + off; off += (bytes + 255) & ~(size_t)255; return p;
  };
  unsigned short* Wih_b = (unsigned short*)alloc((size_t)G4 * EDIM * 2);
  unsigned short* Whh_b = (unsigned short*)alloc((size_t)G4 * HDIM * 2);
  unsigned short* Wo_b  = (unsigned short*)alloc((size_t)VPAD * 1024 * 2);
  unsigned short* xs    = (unsigned short*)alloc((size_t)T_STEPS * BATCH * EDIM * 2);
  unsigned short* XW    = (unsigned short*)alloc((size_t)T_STEPS * BATCH * G4 * 2);
  unsigned short* hs    = (unsigned short*)alloc((size_t)T_STEPS * BATCH * HDIM * 2);
  unsigned short* cs    = (unsigned short*)alloc((size_t)T_STEPS * BATCH * HDIM * 2);
  unsigned short* hxA   = (unsigned short*)alloc((size_t)BATCH * HDIM * 2);
  unsigned short* hxB   = (unsigned short*)alloc((size_t)BATCH * HDIM * 2);
  float* cx             = (float*)alloc((size_t)BATCH * HDIM * 4);
  int* bsz  = (int*)alloc(T_STEPS * 4);
  int* roff = (int*)alloc(T_STEPS * 4);
  int* meta = (int*)alloc(256);
  int* rmap = (int*)alloc(T_STEPS * BATCH * 4);

  k_cvt_w<<<(2 * G4 * EDIM + 255) / 256, 256, 0, stream>>>(W_ih, W_hh, Wih_b, Whh_b);
  k_cvt_wout<<<(VPAD * 1024 + 255) / 256, 256, 0, stream>>>(W_out, Wo_b);
  k_build_xs<<<(T_STEPS * BATCH * EDIM + 255) / 256, 256, 0, stream>>>(img, txt, emb, answer, xs);
  k_init_carry<<<(BATCH * HDIM + 255) / 256, 256, 0, stream>>>(h0, c0, hxA, cx);
  k_lens<<<1, 64, 0, stream>>>(lengths, bsz, roff, meta, rmap);

  k_gemm_xw<<<dim3(1024), 256, 0, stream>>>(xs, Wih_b, b_ih, b_hh, XW);

  unsigned short* hbuf[2] = { hxA, hxB };
  for (int t = 0; t < T_STEPS; t++){
    int do_res = (t >= 2 && (t % 3) == 0) ? 1 : 0;
    int tm2 = (t >= 2) ? (t - 2) : 0;
    k_lstm_step<<<dim3(BATCH / 16, HDIM / 16), 256, 0, stream>>>(
        XW + (size_t)t * BATCH * G4, Whh_b, hbuf[t & 1], hbuf[(t + 1) & 1], cx,
        hs + (size_t)t * BATCH * HDIM, cs + (size_t)t * BATCH * HDIM,
        hs + (size_t)tm2 * BATCH * HDIM, cs + (size_t)tm2 * BATCH * HDIM, do_res);
  }

  k_gemm_out<<<dim3(T_STEPS * BATCH / 256, VPAD / 128), 512, 0, stream>>>(hs, cs, Wo_b, b_out, meta, rmap, out);
}